// Round 12
// baseline (171.169 us; speedup 1.0000x reference)
//
#include <hip/hip_runtime.h>

// Problem constants (match reference.py)
#define NCLASS 100
#define DDIM   512
#define NROWS  131072

#define NBLK    256                 // accum blocks (1 per CU)
#define RPB     (NROWS / NBLK)      // 512 rows per block
#define TROWS   32                  // rows per LDS tile
#define NTILE   (RPB / TROWS)       // 16 tiles
#define THREADS 1024                // 16 waves
#define NWAVES  16
#define F4ROW   (DDIM / 4)          // 128 float4 per row
#define TF4     (TROWS * F4ROW)     // 4096 float4 per tile (64 KB)
#define LDR     (TF4 / THREADS)     // 4 staging float4 per thread
#define MAXCPW  7                   // max classes per wave (ceil(100/16))
#define RBLKS   (NCLASS * 2)        // reduce grid (class x col-half)

__device__ __forceinline__ void gAtomicAddF(float* p, float v) {
    unsafeAtomicAdd(p, v);          // native global_atomic_add_f32
}

// ---------------------------------------------------------------------------
// Kernel 1: sequential-stream accumulation. 256 blocks x 1024 threads; block
// streams 512 contiguous rows through a double-buffered 2x64KB LDS tile
// (reg-staged: issue loads for tile t+1, consume tile t, write, barrier).
// Wave w owns classes [w*100/16,(w+1)*100/16); per tile it scans 32 labels,
// skips non-owned rows via wave-uniform branch, and accumulates owned rows
// from LDS into REGISTER accumulators (compile-time indexed via unrolled j).
// No sort, no gather, no atomics in the hot path. Flush = coalesced stores.
// ---------------------------------------------------------------------------
__global__ __launch_bounds__(THREADS, 4) void icv_accum_kernel(
    const float* __restrict__ feat,      // [NROWS][DDIM]
    const int*   __restrict__ labels,    // [NROWS]
    float*       __restrict__ partials,  // [NCLASS][NBLK][DDIM]
    float*       __restrict__ sqp,       // [NCLASS][NBLK]
    float*       __restrict__ cntp,      // [NCLASS][NBLK]
    float*       __restrict__ cls_norm2, // [NCLASS]
    int*         __restrict__ sync_cnt)
{
    __shared__ float4 s_tile[2][TF4];    // 128 KB
    __shared__ int    s_lab[RPB];        // 2 KB

    const int tid  = threadIdx.x;
    const int wave = tid >> 6;
    const int lane = tid & 63;
    const int b    = blockIdx.x;
    const int row0 = b * RPB;

    if (b == 0) {                        // re-init scalars every call
        if (tid < NCLASS) cls_norm2[tid] = 0.f;
        if (tid == 0) *sync_cnt = 0;
    }
    if (tid < RPB) s_lab[tid] = labels[row0 + tid];   // coalesced

    const int lo   = (wave * NCLASS) >> 4;            // 0,6,12,18,25,...
    const int hi   = ((wave + 1) * NCLASS) >> 4;
    const int nown = hi - lo;                         // 6 or 7

    float4 accA[MAXCPW], accB[MAXCPW];
    float  sqa[MAXCPW], cna[MAXCPW];
    #pragma unroll
    for (int j = 0; j < MAXCPW; ++j) {
        accA[j] = make_float4(0.f, 0.f, 0.f, 0.f);
        accB[j] = make_float4(0.f, 0.f, 0.f, 0.f);
        sqa[j] = 0.f; cna[j] = 0.f;
    }

    const float4* f4    = (const float4*)feat;
    const size_t  gbase = (size_t)row0 * F4ROW;

    // prologue: stage tile 0 (whole tile is one contiguous 64 KB span)
    float4 st[LDR];
    #pragma unroll
    for (int q = 0; q < LDR; ++q) st[q] = f4[gbase + q * THREADS + tid];
    #pragma unroll
    for (int q = 0; q < LDR; ++q) s_tile[0][q * THREADS + tid] = st[q];
    __syncthreads();                     // tile0 + s_lab visible

    for (int t = 0; t < NTILE; ++t) {
        const int buf = t & 1;
        if (t + 1 < NTILE) {             // issue next-tile loads (hide HBM lat)
            const size_t nb = gbase + (size_t)(t + 1) * TF4;
            #pragma unroll
            for (int q = 0; q < LDR; ++q) st[q] = f4[nb + q * THREADS + tid];
        }
        // consume tile t: scan labels, accumulate owned rows from LDS
        const int trow0 = t * TROWS;
        for (int r = 0; r < TROWS; ++r) {
            const int lab = s_lab[trow0 + r];         // broadcast read
            if (lab < lo || lab >= hi) continue;      // wave-uniform skip
            const float4 xa = s_tile[buf][r * F4ROW + lane];       // cols 4l..
            const float4 xb = s_tile[buf][r * F4ROW + 64 + lane];  // cols 256+4l..
            const float sq8 =
                fmaf(xa.x, xa.x, fmaf(xa.y, xa.y, fmaf(xa.z, xa.z, fmaf(xa.w, xa.w,
                fmaf(xb.x, xb.x, fmaf(xb.y, xb.y, fmaf(xb.z, xb.z, xb.w * xb.w)))))));
            #pragma unroll
            for (int j = 0; j < MAXCPW; ++j) {
                if (j < nown && lab == lo + j) {      // uniform; acc idx static
                    accA[j].x += xa.x; accA[j].y += xa.y;
                    accA[j].z += xa.z; accA[j].w += xa.w;
                    accB[j].x += xb.x; accB[j].y += xb.y;
                    accB[j].z += xb.z; accB[j].w += xb.w;
                    sqa[j] += sq8;
                    cna[j] += 1.f;
                }
            }
        }
        __syncthreads();                 // all waves done with tile t-1's buffer
        if (t + 1 < NTILE) {
            #pragma unroll
            for (int q = 0; q < LDR; ++q) s_tile[buf ^ 1][q * THREADS + tid] = st[q];
        }
        __syncthreads();                 // next tile visible
    }

    // flush: per owned class, coalesced float4 stores + wave-reduced sq/cnt
    #pragma unroll
    for (int j = 0; j < MAXCPW; ++j) {
        if (j < nown) {
            const int c = lo + j;
            float4* dst = (float4*)(partials + ((size_t)c * NBLK + b) * DDIM);
            dst[lane]      = accA[j];
            dst[64 + lane] = accB[j];
            float v = sqa[j];
            v += __shfl_xor(v, 32, 64); v += __shfl_xor(v, 16, 64);
            v += __shfl_xor(v,  8, 64); v += __shfl_xor(v,  4, 64);
            v += __shfl_xor(v,  2, 64); v += __shfl_xor(v,  1, 64);
            if (lane == 0) {
                sqp [c * NBLK + b] = v;
                cntp[c * NBLK + b] = cna[j];          // uniform adds -> exact
            }
        }
    }
}

// ---------------------------------------------------------------------------
// Kernel 2: reduce partials. Grid = 100 classes x 2 col-halves (200 blocks x
// 512 threads). Block (c,h): threads split 256 chunk-blocks x 2 subs; sum,
// LDS-combine, square, block-reduce -> atomicAdd cls_norm2[c]. h==0 also
// reduces sq/cnt. Last of 200 computes the final valid-mean (fence+counter).
// ---------------------------------------------------------------------------
__global__ __launch_bounds__(512) void icv_reduce_kernel(
    const float* __restrict__ partials,  // [NCLASS][NBLK][DDIM]
    const float* __restrict__ sqp,       // [NCLASS][NBLK]
    const float* __restrict__ cntp,      // [NCLASS][NBLK]
    float*       __restrict__ cls_norm2, // [NCLASS]
    float*       __restrict__ cls_sq,    // [NCLASS]
    float*       __restrict__ cls_n,     // [NCLASS]
    int*         __restrict__ sync_cnt,
    float*       __restrict__ out)
{
    __shared__ float s_part[2][256];
    __shared__ float red[3][8];
    __shared__ float fin[2][8];
    __shared__ int   s_last;

    const int c    = blockIdx.x >> 1;
    const int h    = blockIdx.x & 1;
    const int t    = threadIdx.x;
    const int wave = t >> 6;
    const int lane = t & 63;
    const int col  = h * 256 + (t & 255);
    const int sub  = t >> 8;                          // 0/1

    // contiguous streaming: class c's panel is [NBLK][DDIM] = 512 KB
    float s = 0.f;
    const float* p = partials + ((size_t)c * NBLK + sub * (NBLK / 2)) * DDIM + col;
    #pragma unroll 8
    for (int ch = 0; ch < NBLK / 2; ++ch)
        s += p[(size_t)ch * DDIM];
    s_part[sub][t & 255] = s;
    __syncthreads();

    float v1 = 0.f;
    if (t < 256) {
        const float tot = s_part[0][t] + s_part[1][t];
        v1 = tot * tot;
    }
    float v2 = 0.f, v3 = 0.f;
    if (h == 0 && t < NBLK) {
        v2 = sqp [c * NBLK + t];
        v3 = cntp[c * NBLK + t];
    }
    #pragma unroll
    for (int off = 32; off > 0; off >>= 1) {
        v1 += __shfl_xor(v1, off, 64);
        v2 += __shfl_xor(v2, off, 64);
        v3 += __shfl_xor(v3, off, 64);
    }
    if (lane == 0) { red[0][wave] = v1; red[1][wave] = v2; red[2][wave] = v3; }
    __syncthreads();

    if (t == 0) {
        float n2 = 0.f, sq = 0.f, n = 0.f;
        #pragma unroll
        for (int w = 0; w < 8; ++w) { n2 += red[0][w]; sq += red[1][w]; n += red[2][w]; }
        gAtomicAddF(&cls_norm2[c], n2);
        if (h == 0) { cls_sq[c] = sq; cls_n[c] = n; }
        __threadfence();                              // release
        const int done = atomicAdd(sync_cnt, 1);      // device-scope
        s_last = (done == RBLKS - 1) ? 1 : 0;
    }
    __syncthreads();

    if (s_last) {                                     // uniform across block
        __threadfence();                              // acquire
        float tv = 0.f, vv = 0.f;
        if (t < NCLASS) {
            const volatile float* vn = cls_norm2;
            const volatile float* vq = cls_sq;
            const volatile float* vc = cls_n;
            const float n    = vc[t];
            const float n2   = vn[t];
            const float sqv  = vq[t];
            const float safe = fmaxf(n, 1.f);
            const float ssd  = sqv - n2 / safe;       // sq - n*||sums/n||^2
            const float tr   = ssd / fmaxf(n - 1.f, 1.f);
            const bool  valid = (n >= 2.f);
            tv = valid ? tr : 0.f;
            vv = valid ? 1.f : 0.f;
        }
        #pragma unroll
        for (int off = 32; off > 0; off >>= 1) {
            tv += __shfl_xor(tv, off, 64);
            vv += __shfl_xor(vv, off, 64);
        }
        if (lane == 0) { fin[0][wave] = tv; fin[1][wave] = vv; }
        __syncthreads();
        if (t == 0) {
            float tot = 0.f, vcn = 0.f;
            #pragma unroll
            for (int w = 0; w < 8; ++w) { tot += fin[0][w]; vcn += fin[1][w]; }
            out[0] = (vcn > 0.f) ? (tot / fmaxf(vcn, 1.f)) : 0.f;
        }
    }
}

extern "C" void kernel_launch(void* const* d_in, const int* in_sizes, int n_in,
                              void* d_out, int out_size, void* d_ws, size_t ws_size,
                              hipStream_t stream) {
    const float* feat   = (const float*)d_in[0];
    const int*   labels = (const int*)d_in[1];
    float* out = (float*)d_out;

    // Workspace (partials/sqp/cntp written unconditionally by every block;
    // cls_* and sync_cnt zero-inited by accum block 0 each call -> no memset):
    float* partials  = (float*)d_ws;                             // 51.2 MB
    float* sqp       = partials + (size_t)NCLASS * NBLK * DDIM;  // 100 KB
    float* cntp      = sqp + NCLASS * NBLK;                      // 100 KB
    float* cls_norm2 = cntp + NCLASS * NBLK;
    float* cls_sq    = cls_norm2 + NCLASS;
    float* cls_n     = cls_sq + NCLASS;
    int*   sync_cnt  = (int*)(cls_n + NCLASS);

    icv_accum_kernel<<<dim3(NBLK), THREADS, 0, stream>>>(
        feat, labels, partials, sqp, cntp, cls_norm2, sync_cnt);
    icv_reduce_kernel<<<dim3(RBLKS), 512, 0, stream>>>(
        partials, sqp, cntp, cls_norm2, cls_sq, cls_n, sync_cnt, out);
}

// Round 13
// 76.355 us; speedup vs baseline: 2.2418x; 2.2418x over previous
//
#include <hip/hip_runtime.h>

// Problem constants (match reference.py)
#define NCLASS 100
#define DDIM   512
#define NROWS  131072

#define CHUNK    2048               // rows per chunk
#define NCHUNK   (NROWS / CHUNK)    // 64
#define NSPLIT   8                  // row-splits per chunk (full row per wave)
#define AWAVES   8                  // waves per accum block
#define WSLOTS   (NSPLIT * AWAVES)  // 64 wave-slots per chunk
#define SPAN     (CHUNK / WSLOTS)   // 32 rows nominal per wave-slot
#define ATHREADS 512
#define STHREADS 1024

// ---------------------------------------------------------------------------
// Kernel 0: per-chunk counting sort of labels (labels-only). Emits class-
// sorted global row ids, class offsets, counts, and 64 per-chunk wave-slot
// class spans. MIDPOINT snapping: class c belongs to the slot containing
// (off[c]+off[c+1])/2 -> quantization error centered vs start-snapping.
// ---------------------------------------------------------------------------
__global__ __launch_bounds__(STHREADS) void icv_sort_kernel(
    const int* __restrict__ labels,
    int* __restrict__ rows_g,   // [NCHUNK][CHUNK] global row ids, class-sorted
    int* __restrict__ off_g,    // [NCHUNK][NCLASS+1]
    int* __restrict__ cnt_p,    // [NCLASS][NCHUNK]  (transposed!)
    int* __restrict__ span_g,   // [NCHUNK][WSLOTS][2]
    int* __restrict__ sync_cnt)
{
    __shared__ int s_cnt[NCLASS];
    __shared__ int s_off[NCLASS + 1];
    __shared__ int s_pos[NCLASS];
    __shared__ int s_scan[128];
    __shared__ int s_rows[CHUNK];

    const int tid   = threadIdx.x;
    const int chunk = blockIdx.x;
    const int row0  = chunk * CHUNK;

    if (tid < NCLASS) s_cnt[tid] = 0;
    if (chunk == 0 && tid == 0) *sync_cnt = 0;     // re-init every call
    __syncthreads();

    const int lab0 = labels[row0 + tid];           // coalesced, 2 rows/thread
    const int lab1 = labels[row0 + STHREADS + tid];
    atomicAdd(&s_cnt[lab0], 1);
    atomicAdd(&s_cnt[lab1], 1);
    __syncthreads();

    // exclusive prefix over 100 bins (128-wide Hillis-Steele)
    if (tid < 128) s_scan[tid] = (tid < NCLASS) ? s_cnt[tid] : 0;
    __syncthreads();
    #pragma unroll
    for (int d = 1; d < 128; d <<= 1) {
        int v = 0;
        if (tid < 128) { v = s_scan[tid]; if (tid >= d) v += s_scan[tid - d]; }
        __syncthreads();
        if (tid < 128) s_scan[tid] = v;
        __syncthreads();
    }
    if (tid < NCLASS) { const int e = s_scan[tid] - s_cnt[tid]; s_off[tid] = e; s_pos[tid] = e; }
    if (tid == NCLASS) s_off[NCLASS] = CHUNK;
    __syncthreads();

    { const int p0 = atomicAdd(&s_pos[lab0], 1); s_rows[p0] = row0 + tid; }
    { const int p1 = atomicAdd(&s_pos[lab1], 1); s_rows[p1] = row0 + STHREADS + tid; }

    // wave-slot class spans via MIDPOINT owner: ow(c) = min(mid_c/SPAN, WSLOTS-1);
    // mid_c monotone in c -> contiguous class ranges, full partition.
    if (tid < WSLOTS) {
        int cf = NCLASS, ce = NCLASS;
        for (int c = 0; c < NCLASS; ++c) {
            const int mid = (s_off[c] + s_off[c + 1]) >> 1;
            int ow = mid / SPAN; if (ow > WSLOTS - 1) ow = WSLOTS - 1;
            if (ow == tid && cf == NCLASS) cf = c;
            if (ow > tid) { ce = c; break; }
        }
        if (cf > ce) cf = ce;                      // empty slot
        span_g[(chunk * WSLOTS + tid) * 2 + 0] = cf;
        span_g[(chunk * WSLOTS + tid) * 2 + 1] = ce;
    }
    __syncthreads();

    rows_g[chunk * CHUNK + tid]            = s_rows[tid];
    rows_g[chunk * CHUNK + STHREADS + tid] = s_rows[STHREADS + tid];
    if (tid < NCLASS) {
        off_g[chunk * (NCLASS + 1) + tid] = s_off[tid];
        cnt_p[tid * NCHUNK + chunk]       = s_cnt[tid];   // transposed store
    }
    if (tid == NCLASS) off_g[chunk * (NCLASS + 1) + NCLASS] = CHUNK;
}

// ---------------------------------------------------------------------------
// Kernel 1: pure streaming accumulation, FULL-ROW granule (R8's best config:
// 64 chunks x 8 splits = 512 blocks of 512 threads, 2 blocks/CU, 2x float4
// per lane per row, depth-4 ring, register accumulation). Only diff vs R8:
// partials layout is [NCLASS][NCHUNK][DDIM] so the reduce streams
// contiguously; flush stores stay 2 KB coalesced per class.
// ---------------------------------------------------------------------------
__global__ __launch_bounds__(ATHREADS, 4) void icv_accum_kernel(
    const float* __restrict__ feat,     // [NROWS][DDIM]
    const int*   __restrict__ rows_g,
    const int*   __restrict__ off_g,
    const int*   __restrict__ span_g,
    float*       __restrict__ sums_p,   // [NCLASS][NCHUNK][DDIM]
    float*       __restrict__ sq_p)     // [NCLASS][NCHUNK]
{
    __shared__ int s_rows[CHUNK];       // 8 KB
    __shared__ int s_off[NCLASS + 1];

    const int tid   = threadIdx.x;
    const int wave  = tid >> 6;
    const int lane  = tid & 63;
    const int b     = blockIdx.x;
    const int chunk = b >> 3;
    const int split = b & 7;

    #pragma unroll
    for (int k = 0; k < CHUNK / ATHREADS; ++k)
        s_rows[k * ATHREADS + tid] = rows_g[chunk * CHUNK + k * ATHREADS + tid];
    if (tid < NCLASS + 1) s_off[tid] = off_g[chunk * (NCLASS + 1) + tid];
    __syncthreads();

    const int ws = split * AWAVES + wave;
    const int cf = span_g[(chunk * WSLOTS + ws) * 2 + 0];
    const int ce = span_g[(chunk * WSLOTS + ws) * 2 + 1];
    const int i0 = s_off[cf];
    const int i1 = s_off[ce];

    const float4* f4 = (const float4*)feat;        // row stride DDIM/4 = 128

    int    c    = cf;
    int    cend = (c < ce) ? s_off[c + 1] : (CHUNK + 1);
    float4 accA = make_float4(0.f, 0.f, 0.f, 0.f);
    float4 accB = make_float4(0.f, 0.f, 0.f, 0.f);
    float  sq   = 0.f;

#define LOADA(idx) f4[(size_t)s_rows[(idx)] * (DDIM / 4) + lane]
#define LOADB(idx) f4[(size_t)s_rows[(idx)] * (DDIM / 4) + 64 + lane]

#define FLUSH() do {                                                          \
        float s_ = sq;                                                        \
        s_ += __shfl_xor(s_, 32, 64); s_ += __shfl_xor(s_, 16, 64);           \
        s_ += __shfl_xor(s_,  8, 64); s_ += __shfl_xor(s_,  4, 64);           \
        s_ += __shfl_xor(s_,  2, 64); s_ += __shfl_xor(s_,  1, 64);           \
        float4* dst_ = (float4*)(sums_p                                       \
            + ((size_t)c * NCHUNK + chunk) * DDIM);                           \
        dst_[lane]      = accA;                                               \
        dst_[64 + lane] = accB;                                               \
        if (lane == 0) sq_p[c * NCHUNK + chunk] = s_;                         \
        accA = make_float4(0.f, 0.f, 0.f, 0.f);                               \
        accB = make_float4(0.f, 0.f, 0.f, 0.f);                               \
        sq = 0.f;                                                             \
        ++c;                                                                  \
        cend = (c < ce) ? s_off[c + 1] : (CHUNK + 1);                         \
    } while (0)

#define STEP(K, RA, RB) {                                                     \
        const int i_ = ib + (K);                                              \
        if (i_ < i1) {                                                        \
            while (i_ >= cend) FLUSH();                                       \
            const float4 a_ = RA;                                             \
            const float4 b_ = RB;                                             \
            const int ip_ = i_ + 4;                                           \
            if (ip_ < i1) { RA = LOADA(ip_); RB = LOADB(ip_); }               \
            accA.x += a_.x; accA.y += a_.y; accA.z += a_.z; accA.w += a_.w;   \
            accB.x += b_.x; accB.y += b_.y; accB.z += b_.z; accB.w += b_.w;   \
            sq = fmaf(a_.x, a_.x, fmaf(a_.y, a_.y,                            \
                 fmaf(a_.z, a_.z, fmaf(a_.w, a_.w, sq))));                    \
            sq = fmaf(b_.x, b_.x, fmaf(b_.y, b_.y,                            \
                 fmaf(b_.z, b_.z, fmaf(b_.w, b_.w, sq))));                    \
        }                                                                     \
    }

    float4 r0a = make_float4(0.f, 0.f, 0.f, 0.f), r0b = r0a;
    float4 r1a = r0a, r1b = r0a, r2a = r0a, r2b = r0a, r3a = r0a, r3b = r0a;
    if (i0 + 0 < i1) { r0a = LOADA(i0 + 0); r0b = LOADB(i0 + 0); }
    if (i0 + 1 < i1) { r1a = LOADA(i0 + 1); r1b = LOADB(i0 + 1); }
    if (i0 + 2 < i1) { r2a = LOADA(i0 + 2); r2b = LOADB(i0 + 2); }
    if (i0 + 3 < i1) { r3a = LOADA(i0 + 3); r3b = LOADB(i0 + 3); }

    for (int ib = i0; ib < i1; ib += 4) {
        STEP(0, r0a, r0b)
        STEP(1, r1a, r1b)
        STEP(2, r2a, r2b)
        STEP(3, r3a, r3b)
    }
    while (c < ce) FLUSH();                        // tail incl. empty classes
#undef STEP
#undef FLUSH
#undef LOADA
#undef LOADB
}

// ---------------------------------------------------------------------------
// Kernel 2: per-class reduction of partials -> trace/valid, fused with the
// final valid-mean via last-block pattern. Block c streams its class's
// CONTIGUOUS 128 KB panel ([NCHUNK][DDIM]) -- fully coalesced (vs R8's
// 256 B granules at stride 205 KB).
// ---------------------------------------------------------------------------
__global__ __launch_bounds__(512) void icv_reduce_kernel(
    const float* __restrict__ sums_p,   // [NCLASS][NCHUNK][DDIM]
    const float* __restrict__ sq_p,     // [NCLASS][NCHUNK]
    const int*   __restrict__ cnt_p,    // [NCLASS][NCHUNK]
    float*       __restrict__ cls_out,  // [NCLASS][2]
    int*         __restrict__ sync_cnt,
    float*       __restrict__ out)
{
    __shared__ float red[3][8];
    __shared__ float fin[2][8];
    __shared__ int   s_last;

    const int c    = blockIdx.x;
    const int t    = threadIdx.x;
    const int wave = t >> 6;
    const int lane = t & 63;

    // thread t owns column t of class c; panel is contiguous 128 KB
    float s = 0.f;
    const float* p = sums_p + (size_t)c * NCHUNK * DDIM + t;
    #pragma unroll 8
    for (int ch = 0; ch < NCHUNK; ++ch)
        s += p[(size_t)ch * DDIM];

    float v1 = s * s;                                          // -> ||sum_c||^2
    float v2 = (t < NCHUNK) ? sq_p[c * NCHUNK + t] : 0.f;
    float v3 = (t < NCHUNK) ? (float)cnt_p[c * NCHUNK + t] : 0.f;
    #pragma unroll
    for (int off = 32; off > 0; off >>= 1) {
        v1 += __shfl_xor(v1, off, 64);
        v2 += __shfl_xor(v2, off, 64);
        v3 += __shfl_xor(v3, off, 64);
    }
    if (lane == 0) { red[0][wave] = v1; red[1][wave] = v2; red[2][wave] = v3; }
    __syncthreads();

    if (t == 0) {
        float n2 = 0.f, sq = 0.f, n = 0.f;
        #pragma unroll
        for (int w = 0; w < 8; ++w) { n2 += red[0][w]; sq += red[1][w]; n += red[2][w]; }
        const float safe  = fmaxf(n, 1.f);
        const float ssd   = sq - n2 / safe;        // sq - n*||sums/n||^2
        const float trace = ssd / fmaxf(n - 1.f, 1.f);
        const bool  valid = (n >= 2.f);
        cls_out[c * 2 + 0] = valid ? trace : 0.f;
        cls_out[c * 2 + 1] = valid ? 1.f : 0.f;
        __threadfence();                           // release class result
        const int done = atomicAdd(sync_cnt, 1);   // device-scope
        s_last = (done == NCLASS - 1) ? 1 : 0;
    }
    __syncthreads();

    if (s_last) {                                  // uniform across block
        __threadfence();                           // acquire others' results
        float tv = 0.f, vv = 0.f;
        if (t < NCLASS) {
            const volatile float* cv = (const volatile float*)cls_out;
            tv = cv[t * 2 + 0];
            vv = cv[t * 2 + 1];
        }
        #pragma unroll
        for (int off = 32; off > 0; off >>= 1) {
            tv += __shfl_xor(tv, off, 64);
            vv += __shfl_xor(vv, off, 64);
        }
        if (lane == 0) { fin[0][wave] = tv; fin[1][wave] = vv; }
        __syncthreads();
        if (t == 0) {
            float tot = 0.f, vc = 0.f;
            #pragma unroll
            for (int w = 0; w < 8; ++w) { tot += fin[0][w]; vc += fin[1][w]; }
            out[0] = (vc > 0.f) ? (tot / fmaxf(vc, 1.f)) : 0.f;
        }
    }
}

extern "C" void kernel_launch(void* const* d_in, const int* in_sizes, int n_in,
                              void* d_out, int out_size, void* d_ws, size_t ws_size,
                              hipStream_t stream) {
    const float* feat   = (const float*)d_in[0];
    const int*   labels = (const int*)d_in[1];
    float* out = (float*)d_out;

    // Workspace (all slots written unconditionally every call -> no memset):
    float* sums_p  = (float*)d_ws;                              // 13.1 MB
    float* sq_p    = sums_p + (size_t)NCLASS * NCHUNK * DDIM;   // 26 KB
    int*   cnt_p   = (int*)(sq_p + NCLASS * NCHUNK);            // 26 KB
    int*   rows_g  = cnt_p + NCLASS * NCHUNK;                   // 524 KB
    int*   off_g   = rows_g + NCHUNK * CHUNK;                   // 26 KB
    int*   span_g  = off_g + NCHUNK * (NCLASS + 1);             // 32 KB
    float* cls_out = (float*)(span_g + NCHUNK * WSLOTS * 2);
    int*   sync_cnt= (int*)(cls_out + NCLASS * 2);

    icv_sort_kernel<<<dim3(NCHUNK), STHREADS, 0, stream>>>(
        labels, rows_g, off_g, cnt_p, span_g, sync_cnt);
    icv_accum_kernel<<<dim3(NCHUNK * NSPLIT), ATHREADS, 0, stream>>>(
        feat, rows_g, off_g, span_g, sums_p, sq_p);
    icv_reduce_kernel<<<dim3(NCLASS), 512, 0, stream>>>(
        sums_p, sq_p, cnt_p, cls_out, sync_cnt, out);
}

// Round 14
// 75.737 us; speedup vs baseline: 2.2600x; 1.0082x over previous
//
#include <hip/hip_runtime.h>

// Problem constants (match reference.py)
#define CHUNK    2048               // rows per chunk
#define NCLASS 100
#define DDIM   512
#define NROWS  131072

#define NCHUNK   (NROWS / CHUNK)    // 64
#define NSPLIT   8                  // row-splits per chunk (full row per wave)
#define AWAVES   8                  // waves per accum block
#define WSLOTS   (NSPLIT * AWAVES)  // 64 wave-slots per chunk
#define SPAN     (CHUNK / WSLOTS)   // 32 rows nominal per wave-slot
#define ATHREADS 512
#define STHREADS 1024

// ---------------------------------------------------------------------------
// Kernel 0: per-chunk counting sort of labels (labels-only). Emits class-
// sorted global row ids, class offsets, counts, and 64 per-chunk wave-slot
// class spans (slot s owns classes whose segment STARTS in [32s, 32(s+1))).
// Each class belongs to exactly one slot -> every partial written exactly once.
// ---------------------------------------------------------------------------
__global__ __launch_bounds__(STHREADS) void icv_sort_kernel(
    const int* __restrict__ labels,
    int* __restrict__ rows_g,   // [NCHUNK][CHUNK] global row ids, class-sorted
    int* __restrict__ off_g,    // [NCHUNK][NCLASS+1]
    int* __restrict__ cnt_p,    // [NCHUNK][NCLASS]
    int* __restrict__ span_g,   // [NCHUNK][WSLOTS][2]
    int* __restrict__ sync_cnt)
{
    __shared__ int s_cnt[NCLASS];
    __shared__ int s_off[NCLASS + 1];
    __shared__ int s_pos[NCLASS];
    __shared__ int s_scan[128];
    __shared__ int s_rows[CHUNK];

    const int tid   = threadIdx.x;
    const int chunk = blockIdx.x;
    const int row0  = chunk * CHUNK;

    if (tid < NCLASS) s_cnt[tid] = 0;
    if (chunk == 0 && tid == 0) *sync_cnt = 0;     // re-init every call
    __syncthreads();

    const int lab0 = labels[row0 + tid];           // coalesced, 2 rows/thread
    const int lab1 = labels[row0 + STHREADS + tid];
    atomicAdd(&s_cnt[lab0], 1);
    atomicAdd(&s_cnt[lab1], 1);
    __syncthreads();

    // exclusive prefix over 100 bins (128-wide Hillis-Steele)
    if (tid < 128) s_scan[tid] = (tid < NCLASS) ? s_cnt[tid] : 0;
    __syncthreads();
    #pragma unroll
    for (int d = 1; d < 128; d <<= 1) {
        int v = 0;
        if (tid < 128) { v = s_scan[tid]; if (tid >= d) v += s_scan[tid - d]; }
        __syncthreads();
        if (tid < 128) s_scan[tid] = v;
        __syncthreads();
    }
    if (tid < NCLASS) { const int e = s_scan[tid] - s_cnt[tid]; s_off[tid] = e; s_pos[tid] = e; }
    if (tid == NCLASS) s_off[NCLASS] = CHUNK;
    __syncthreads();

    { const int p0 = atomicAdd(&s_pos[lab0], 1); s_rows[p0] = row0 + tid; }
    { const int p1 = atomicAdd(&s_pos[lab1], 1); s_rows[p1] = row0 + STHREADS + tid; }

    // wave-slot class spans: owner(c) = min(s_off[c]/SPAN, WSLOTS-1);
    // owner is non-decreasing in c -> contiguous class ranges, full partition.
    if (tid < WSLOTS) {
        int cf = NCLASS, ce = NCLASS;
        for (int c = 0; c < NCLASS; ++c) {
            int ow = s_off[c] / SPAN; if (ow > WSLOTS - 1) ow = WSLOTS - 1;
            if (ow == tid && cf == NCLASS) cf = c;
            if (ow > tid) { ce = c; break; }
        }
        if (cf > ce) cf = ce;                      // empty slot
        span_g[(chunk * WSLOTS + tid) * 2 + 0] = cf;
        span_g[(chunk * WSLOTS + tid) * 2 + 1] = ce;
    }
    __syncthreads();

    rows_g[chunk * CHUNK + tid]            = s_rows[tid];
    rows_g[chunk * CHUNK + STHREADS + tid] = s_rows[STHREADS + tid];
    if (tid < NCLASS) {
        off_g[chunk * (NCLASS + 1) + tid] = s_off[tid];
        cnt_p[chunk * NCLASS + tid]       = s_cnt[tid];
    }
    if (tid == NCLASS) off_g[chunk * (NCLASS + 1) + NCLASS] = CHUNK;
}

// ---------------------------------------------------------------------------
// Kernel 1: pure streaming accumulation, FULL-ROW granule. Grid = 64 chunks
// x 8 splits = 512 blocks of 512 threads (2 blocks/CU). Wave-slot ws =
// split*8 + wave streams its snapped class span; each row is one contiguous
// 2 KB read (2x float4 per lane), depth-4 ring (8 KB in flight per wave),
// register accumulation, per-class flush = plain coalesced stores.
// ---------------------------------------------------------------------------
__global__ __launch_bounds__(ATHREADS, 4) void icv_accum_kernel(
    const float* __restrict__ feat,     // [NROWS][DDIM]
    const int*   __restrict__ rows_g,
    const int*   __restrict__ off_g,
    const int*   __restrict__ span_g,
    float*       __restrict__ sums_p,   // [NCHUNK][NCLASS][DDIM]
    float*       __restrict__ sq_p)     // [NCHUNK][NCLASS]
{
    __shared__ int s_rows[CHUNK];       // 8 KB
    __shared__ int s_off[NCLASS + 1];

    const int tid   = threadIdx.x;
    const int wave  = tid >> 6;
    const int lane  = tid & 63;
    const int b     = blockIdx.x;
    const int chunk = b >> 3;
    const int split = b & 7;

    #pragma unroll
    for (int k = 0; k < CHUNK / ATHREADS; ++k)
        s_rows[k * ATHREADS + tid] = rows_g[chunk * CHUNK + k * ATHREADS + tid];
    if (tid < NCLASS + 1) s_off[tid] = off_g[chunk * (NCLASS + 1) + tid];
    __syncthreads();

    const int ws = split * AWAVES + wave;
    const int cf = span_g[(chunk * WSLOTS + ws) * 2 + 0];
    const int ce = span_g[(chunk * WSLOTS + ws) * 2 + 1];
    const int i0 = s_off[cf];
    const int i1 = s_off[ce];

    const float4* f4 = (const float4*)feat;        // row stride DDIM/4 = 128

    int    c    = cf;
    int    cend = (c < ce) ? s_off[c + 1] : (CHUNK + 1);
    float4 accA = make_float4(0.f, 0.f, 0.f, 0.f);
    float4 accB = make_float4(0.f, 0.f, 0.f, 0.f);
    float  sq   = 0.f;

#define LOADA(idx) f4[(size_t)s_rows[(idx)] * (DDIM / 4) + lane]
#define LOADB(idx) f4[(size_t)s_rows[(idx)] * (DDIM / 4) + 64 + lane]

#define FLUSH() do {                                                          \
        float s_ = sq;                                                        \
        s_ += __shfl_xor(s_, 32, 64); s_ += __shfl_xor(s_, 16, 64);           \
        s_ += __shfl_xor(s_,  8, 64); s_ += __shfl_xor(s_,  4, 64);           \
        s_ += __shfl_xor(s_,  2, 64); s_ += __shfl_xor(s_,  1, 64);           \
        float4* dst_ = (float4*)(sums_p                                       \
            + ((size_t)(chunk * NCLASS + c) * DDIM));                         \
        dst_[lane]      = accA;                                               \
        dst_[64 + lane] = accB;                                               \
        if (lane == 0) sq_p[chunk * NCLASS + c] = s_;                         \
        accA = make_float4(0.f, 0.f, 0.f, 0.f);                               \
        accB = make_float4(0.f, 0.f, 0.f, 0.f);                               \
        sq = 0.f;                                                             \
        ++c;                                                                  \
        cend = (c < ce) ? s_off[c + 1] : (CHUNK + 1);                         \
    } while (0)

#define STEP(K, RA, RB) {                                                     \
        const int i_ = ib + (K);                                              \
        if (i_ < i1) {                                                        \
            while (i_ >= cend) FLUSH();                                       \
            const float4 a_ = RA;                                             \
            const float4 b_ = RB;                                             \
            const int ip_ = i_ + 4;                                           \
            if (ip_ < i1) { RA = LOADA(ip_); RB = LOADB(ip_); }               \
            accA.x += a_.x; accA.y += a_.y; accA.z += a_.z; accA.w += a_.w;   \
            accB.x += b_.x; accB.y += b_.y; accB.z += b_.z; accB.w += b_.w;   \
            sq = fmaf(a_.x, a_.x, fmaf(a_.y, a_.y,                            \
                 fmaf(a_.z, a_.z, fmaf(a_.w, a_.w, sq))));                    \
            sq = fmaf(b_.x, b_.x, fmaf(b_.y, b_.y,                            \
                 fmaf(b_.z, b_.z, fmaf(b_.w, b_.w, sq))));                    \
        }                                                                     \
    }

    float4 r0a = make_float4(0.f, 0.f, 0.f, 0.f), r0b = r0a;
    float4 r1a = r0a, r1b = r0a, r2a = r0a, r2b = r0a, r3a = r0a, r3b = r0a;
    if (i0 + 0 < i1) { r0a = LOADA(i0 + 0); r0b = LOADB(i0 + 0); }
    if (i0 + 1 < i1) { r1a = LOADA(i0 + 1); r1b = LOADB(i0 + 1); }
    if (i0 + 2 < i1) { r2a = LOADA(i0 + 2); r2b = LOADB(i0 + 2); }
    if (i0 + 3 < i1) { r3a = LOADA(i0 + 3); r3b = LOADB(i0 + 3); }

    for (int ib = i0; ib < i1; ib += 4) {
        STEP(0, r0a, r0b)
        STEP(1, r1a, r1b)
        STEP(2, r2a, r2b)
        STEP(3, r3a, r3b)
    }
    while (c < ce) FLUSH();                        // tail incl. empty classes
#undef STEP
#undef FLUSH
#undef LOADA
#undef LOADB
}

// ---------------------------------------------------------------------------
// Kernel 2: per-class reduction of partials -> trace/valid, fused with the
// final valid-mean via last-block pattern (device-scope fence + atomic).
// ---------------------------------------------------------------------------
__global__ __launch_bounds__(512) void icv_reduce_kernel(
    const float* __restrict__ sums_p,   // [NCHUNK][NCLASS][DDIM]
    const float* __restrict__ sq_p,     // [NCHUNK][NCLASS]
    const int*   __restrict__ cnt_p,    // [NCHUNK][NCLASS]
    float*       __restrict__ cls_out,  // [NCLASS][2]
    int*         __restrict__ sync_cnt,
    float*       __restrict__ out)
{
    __shared__ float red[3][8];
    __shared__ float fin[2][8];
    __shared__ int   s_last;

    const int c    = blockIdx.x;
    const int t    = threadIdx.x;
    const int wave = t >> 6;
    const int lane = t & 63;

    // thread t owns column t of class c, summed over chunks
    float s = 0.f;
    const float* p = sums_p + (size_t)c * DDIM + t;
    #pragma unroll 8
    for (int ch = 0; ch < NCHUNK; ++ch)
        s += p[(size_t)ch * (NCLASS * DDIM)];

    float v1 = s * s;                                          // -> ||sum_c||^2
    float v2 = (t < NCHUNK) ? sq_p[t * NCLASS + c] : 0.f;
    float v3 = (t < NCHUNK) ? (float)cnt_p[t * NCLASS + c] : 0.f;
    #pragma unroll
    for (int off = 32; off > 0; off >>= 1) {
        v1 += __shfl_xor(v1, off, 64);
        v2 += __shfl_xor(v2, off, 64);
        v3 += __shfl_xor(v3, off, 64);
    }
    if (lane == 0) { red[0][wave] = v1; red[1][wave] = v2; red[2][wave] = v3; }
    __syncthreads();

    if (t == 0) {
        float n2 = 0.f, sq = 0.f, n = 0.f;
        #pragma unroll
        for (int w = 0; w < 8; ++w) { n2 += red[0][w]; sq += red[1][w]; n += red[2][w]; }
        const float safe  = fmaxf(n, 1.f);
        const float ssd   = sq - n2 / safe;        // sq - n*||sums/n||^2
        const float trace = ssd / fmaxf(n - 1.f, 1.f);
        const bool  valid = (n >= 2.f);
        cls_out[c * 2 + 0] = valid ? trace : 0.f;
        cls_out[c * 2 + 1] = valid ? 1.f : 0.f;
        __threadfence();                           // release class result
        const int done = atomicAdd(sync_cnt, 1);   // device-scope
        s_last = (done == NCLASS - 1) ? 1 : 0;
    }
    __syncthreads();

    if (s_last) {                                  // uniform across block
        __threadfence();                           // acquire others' results
        float tv = 0.f, vv = 0.f;
        if (t < NCLASS) {
            const volatile float* cv = (const volatile float*)cls_out;
            tv = cv[t * 2 + 0];
            vv = cv[t * 2 + 1];
        }
        #pragma unroll
        for (int off = 32; off > 0; off >>= 1) {
            tv += __shfl_xor(tv, off, 64);
            vv += __shfl_xor(vv, off, 64);
        }
        if (lane == 0) { fin[0][wave] = tv; fin[1][wave] = vv; }
        __syncthreads();
        if (t == 0) {
            float tot = 0.f, vc = 0.f;
            #pragma unroll
            for (int w = 0; w < 8; ++w) { tot += fin[0][w]; vc += fin[1][w]; }
            out[0] = (vc > 0.f) ? (tot / fmaxf(vc, 1.f)) : 0.f;
        }
    }
}

extern "C" void kernel_launch(void* const* d_in, const int* in_sizes, int n_in,
                              void* d_out, int out_size, void* d_ws, size_t ws_size,
                              hipStream_t stream) {
    const float* feat   = (const float*)d_in[0];
    const int*   labels = (const int*)d_in[1];
    float* out = (float*)d_out;

    // Workspace (all slots written unconditionally every call -> no memset):
    float* sums_p  = (float*)d_ws;                              // 13.1 MB
    float* sq_p    = sums_p + (size_t)NCHUNK * NCLASS * DDIM;   // 26 KB
    int*   cnt_p   = (int*)(sq_p + NCHUNK * NCLASS);            // 26 KB
    int*   rows_g  = cnt_p + NCHUNK * NCLASS;                   // 524 KB
    int*   off_g   = rows_g + NCHUNK * CHUNK;                   // 26 KB
    int*   span_g  = off_g + NCHUNK * (NCLASS + 1);             // 32 KB
    float* cls_out = (float*)(span_g + NCHUNK * WSLOTS * 2);
    int*   sync_cnt= (int*)(cls_out + NCLASS * 2);

    icv_sort_kernel<<<dim3(NCHUNK), STHREADS, 0, stream>>>(
        labels, rows_g, off_g, cnt_p, span_g, sync_cnt);
    icv_accum_kernel<<<dim3(NCHUNK * NSPLIT), ATHREADS, 0, stream>>>(
        feat, rows_g, off_g, span_g, sums_p, sq_p);
    icv_reduce_kernel<<<dim3(NCLASS), 512, 0, stream>>>(
        sums_p, sq_p, cnt_p, cls_out, sync_cnt, out);
}